// Round 6
// baseline (681.536 us; speedup 1.0000x reference)
//
#include <hip/hip_runtime.h>
#include <math.h>

constexpr int NN = 50000;
constexpr int NE = 1600000;
constexpr float LN_EPS = 1e-5f;

typedef __attribute__((ext_vector_type(8))) short short8;
typedef __attribute__((ext_vector_type(4))) float f32x4;

__device__ __forceinline__ short f2bf(float f)
{
    unsigned u = __builtin_bit_cast(unsigned, f);
    u += 0x7fffu + ((u >> 16) & 1u);          // RNE
    return (short)(u >> 16);
}

__device__ __forceinline__ float2 bf2x2(unsigned p)
{
    float2 r;
    r.x = __builtin_bit_cast(float, p << 16);          // low ushort
    r.y = __builtin_bit_cast(float, p & 0xffff0000u);  // high ushort
    return r;
}

// ---------------------------------------------------------------- degree (int)
__global__ void degi_kernel(const int* __restrict__ col, int* __restrict__ deg)
{
    int e = blockIdx.x * 256 + threadIdx.x;
    if (e < NE) atomicAdd(&deg[col[e]], 1);
}

__global__ void dis_kernel(const int* __restrict__ degi, float* __restrict__ dis)
{
    int i = blockIdx.x * 256 + threadIdx.x;
    if (i < NN) dis[i] = rsqrtf((float)degi[i] + 1.0f);   // +1 = self loop
}

// ---------------------------------------------------------------- exclusive scan (single block)
__global__ __launch_bounds__(1024) void scan_kernel(const int* __restrict__ deg,
                                                    int* __restrict__ off)
{
    __shared__ int part[1024];
    const int t = threadIdx.x;
    constexpr int CH = (NN + 1023) / 1024;     // 49
    const int base = t * CH;
    int s = 0;
    for (int j = 0; j < CH; ++j) { int i = base + j; if (i < NN) s += deg[i]; }
    part[t] = s;
    __syncthreads();
    for (int d = 1; d < 1024; d <<= 1) {
        int add = (t >= d) ? part[t - d] : 0;
        __syncthreads();
        part[t] += add;
        __syncthreads();
    }
    int run = part[t] - s;
    for (int j = 0; j < CH; ++j) {
        int i = base + j;
        if (i < NN) { off[i] = run; run += deg[i]; }
    }
    if (t == 1023) off[NN] = part[1023];
}

// ---------------------------------------------------------------- CSR fill
__global__ void csr_fill(const int* __restrict__ ei, const int* __restrict__ off,
                         int* __restrict__ cur, int* __restrict__ rows)
{
    int e = blockIdx.x * 256 + threadIdx.x;
    if (e >= NE) return;
    int r = ei[e];
    int c = ei[NE + e];
    int p = off[c] + atomicAdd(&cur[c], 1);
    rows[p] = r;
}

// ---------------------------------------------------------------- B-fragment pack
// wtf[((kk*OT + ot)*64 + lane)*8 + j8]:
//   g4 = lane>>4; s = kk*8 + j8; f = g4*(D/4) + s/5; g5 = s%5; o = ot*16 + (lane&15)
//   g5<4 -> sw[o][f*4+g5], g5==4 -> bw[o][f]
__global__ void pack_frag(const float* __restrict__ sw, const float* __restrict__ bw,
                          short* __restrict__ wtf, int D, int OT, int DO, int total)
{
    int idx = blockIdx.x * 256 + threadIdx.x;
    if (idx >= total) return;
    int j8   = idx & 7;
    int lane = (idx >> 3) & 63;
    int rest = idx >> 9;               // kk*OT + ot
    int ot = rest % OT, kk = rest / OT;
    int g4 = lane >> 4;
    int s  = kk * 8 + j8;
    int f  = g4 * (D / 4) + s / 5;
    int g5 = s % 5;
    int o  = ot * 16 + (lane & 15);
    float val = 0.f;
    if (o < DO) val = (g5 < 4) ? sw[o * D * 4 + f * 4 + g5] : bw[o * D + f];
    wtf[idx] = f2bf(val);
}

// ---------------------------------------------------------------- FastKAN layer (register-A MFMA)
// NODES nodes/block, block = NODES*4 threads = NODES/16 waves.
// Phase A: 4 threads/node stage packed (bf16(hn)<<16 | bf16(silu)) per (node,f) in LDS.
// Phase 2: wave wv owns nodes wv*16..+15; lane (m,g4) builds A short8 in regs per kk
//          from 2-3 LDS b32 reads; B streamed from global; MFMA accumulate.
template<int D, int DO, int OT, int KKC, int NODES>
__global__ __launch_bounds__(NODES * 4) void fkan_reg(
    const float* __restrict__ s0, const float* __restrict__ s1, const float* __restrict__ s2,
    const float* __restrict__ ln_g, const float* __restrict__ ln_b,
    const short* __restrict__ wtf, const float* __restrict__ sb, const float* __restrict__ bb,
    short* __restrict__ out)
{
    constexpr int BW  = D / 4;         // features per g4-block
    constexpr int GBS = BW + 1;        // g4-block stride (u32)
    constexpr int RS  = 4 * GBS + 1;   // node row stride (u32)
    __shared__ unsigned pkL[NODES * RS];

    const int tid = threadIdx.x;

    // ---- phase A: LN + silu, packed into LDS
    {
        const int anode = tid >> 2, q = tid & 3;
        const int gnode = blockIdx.x * NODES + anode;
        const int snode = (gnode < NN) ? gnode : (NN - 1);
        unsigned* prow = &pkL[anode * RS + q * GBS];
        float sum = 0.f, sq = 0.f;
        #pragma unroll
        for (int i4 = 0; i4 < BW / 4; ++i4) {
            int f = q * BW + i4 * 4;
            const float* src = (D == 128) ? s0 : ((f < 128) ? s0 : (f < 256) ? s1 : s2);
            float4 v = *(const float4*)&src[snode * 128 + (f & 127)];
            sum += (v.x + v.y) + (v.z + v.w);
            sq  += (v.x * v.x + v.y * v.y) + (v.z * v.z + v.w * v.w);
            prow[i4 * 4 + 0] = __builtin_bit_cast(unsigned, v.x);
            prow[i4 * 4 + 1] = __builtin_bit_cast(unsigned, v.y);
            prow[i4 * 4 + 2] = __builtin_bit_cast(unsigned, v.z);
            prow[i4 * 4 + 3] = __builtin_bit_cast(unsigned, v.w);
        }
        sum += __shfl_xor(sum, 1); sum += __shfl_xor(sum, 2);
        sq  += __shfl_xor(sq, 1);  sq  += __shfl_xor(sq, 2);
        float mu   = sum * (1.0f / D);
        float var  = sq * (1.0f / D) - mu * mu;
        float rstd = rsqrtf(var + LN_EPS);
        #pragma unroll 4
        for (int i = 0; i < BW; ++i) {
            int f = q * BW + i;
            float v  = __builtin_bit_cast(float, prow[i]);
            float hn = (v - mu) * rstd * ln_g[f] + ln_b[f];
            float sl = v / (1.0f + __expf(-v));
            prow[i] = ((unsigned)(unsigned short)f2bf(hn) << 16)
                    | ((unsigned)(unsigned short)f2bf(sl) & 0xffffu);
        }
    }
    __syncthreads();

    // ---- phase 2: register-A MFMA
    const int wv = tid >> 6, lane = tid & 63;
    const int m = lane & 15, g4 = lane >> 4;
    const unsigned* pkb = &pkL[(wv * 16 + m) * RS + g4 * GBS];

    f32x4 acc[OT];
    #pragma unroll
    for (int ot = 0; ot < OT; ++ot) acc[ot] = f32x4{0.f, 0.f, 0.f, 0.f};

    union AU { unsigned u[4]; short8 s; };

    for (int per = 0; per < KKC / 5; ++per) {          // 5 kk = 40 slots = 8 features
        const unsigned* pp = pkb + per * 8;
        const short* bp = wtf + ((per * 5) * OT * 512) + lane * 8;
        #pragma unroll
        for (int c = 0; c < 5; ++c) {
            unsigned p[3];
            float h75[3];
            // features needed by this kk: fl_in = (c*8 .. c*8+7)/5
            constexpr int FL0[5] = {0, 1, 3, 4, 6};
            constexpr int NF[5]  = {2, 3, 2, 3, 2};
            #pragma unroll
            for (int i = 0; i < 3; ++i) {
                if (i < NF[c]) {
                    p[i] = pp[FL0[c] + i];
                    h75[i] = __builtin_bit_cast(float, p[i] & 0xffff0000u) * 0.75f;
                }
            }
            AU a;
            #pragma unroll
            for (int i = 0; i < 4; ++i) {
                unsigned v2[2];
                #pragma unroll
                for (int h = 0; h < 2; ++h) {
                    int sl = c * 8 + 2 * i + h;        // compile-time
                    int fl = sl / 5 - FL0[c];
                    int g  = sl % 5;
                    if (g == 4) {
                        v2[h] = p[fl] & 0xffffu;
                    } else {
                        float t = h75[fl] + (1.5f - (float)g);
                        float e = __expf(-t * t);
                        v2[h] = (unsigned)(unsigned short)f2bf(e);
                    }
                }
                a.u[i] = (v2[0] & 0xffffu) | (v2[1] << 16);
            }
            #pragma unroll
            for (int ot = 0; ot < OT; ++ot) {
                short8 b = *(const short8*)(bp + (c * OT + ot) * 512);
                acc[ot] = __builtin_amdgcn_mfma_f32_16x16x32_bf16(a.s, b, acc[ot], 0, 0, 0);
            }
        }
    }

    // ---- epilogue: bf16 write, C/D: col=lane&15, row=(lane>>4)*4+reg
    const int nrow0 = blockIdx.x * NODES + wv * 16 + g4 * 4;
    #pragma unroll
    for (int ot = 0; ot < OT; ++ot) {
        int o = ot * 16 + m;
        if (o < DO) {
            float cb = sb[o] + bb[o];
            #pragma unroll
            for (int r = 0; r < 4; ++r) {
                int nr = nrow0 + r;
                if (nr < NN) out[nr * DO + o] = f2bf(acc[ot][r] + cb);
            }
        }
    }
}

// ---------------------------------------------------------------- CSR gather (bf16 rows)
template<int DO>
__global__ __launch_bounds__(64) void agg_gather_bf16(
    const int* __restrict__ off, const int* __restrict__ rows,
    const float* __restrict__ dis, const short* __restrict__ hwb,
    const float* __restrict__ bias, float* __restrict__ out)
{
    constexpr int ACT = DO / 2;        // active compute lanes
    const int n   = blockIdx.x;
    const int tid = threadIdx.x;
    __shared__ int   srow[64];
    __shared__ float swgt[64];

    const int e0 = off[n], e1 = off[n + 1];
    const float dn = dis[n];
    float ax = 0.f, ay = 0.f;
    if (tid < ACT) {
        unsigned p = *(const unsigned*)&hwb[n * DO + 2 * tid];
        float2 v = bf2x2(p);
        ax = dn * dn * v.x + bias[2 * tid];
        ay = dn * dn * v.y + bias[2 * tid + 1];
    }

    for (int t0 = e0; t0 < e1; t0 += 64) {
        const int nt = min(64, e1 - t0);
        if (tid < nt) {
            int r = rows[t0 + tid];
            srow[tid] = r;
            swgt[tid] = dn * dis[r];
        }
        __syncthreads();
        if (tid < ACT) {
            #pragma unroll 4
            for (int j = 0; j < nt; ++j) {
                unsigned p = *(const unsigned*)&hwb[srow[j] * DO + 2 * tid];
                float2 v = bf2x2(p);
                float w = swgt[j];
                ax += w * v.x;
                ay += w * v.y;
            }
        }
        __syncthreads();
    }
    if (tid < ACT) {
        out[n * DO + 2 * tid]     = ax;
        out[n * DO + 2 * tid + 1] = ay;
    }
}

// ---------------------------------------------------------------- batchnorm
__global__ void bn_stats(const float* __restrict__ h, float* __restrict__ stats)
{
    __shared__ float s1[256], s2[256];
    int c = threadIdx.x & 127;
    int half = threadIdx.x >> 7;
    float sum = 0.f, sq = 0.f;
    for (int n = blockIdx.x * 2 + half; n < NN; n += 512) {
        float v = h[n * 128 + c];
        sum += v; sq += v * v;
    }
    s1[threadIdx.x] = sum; s2[threadIdx.x] = sq;
    __syncthreads();
    if (half == 0) {
        s1[c] += s1[c + 128]; s2[c] += s2[c + 128];
        atomicAdd(&stats[c],        s1[c]);
        atomicAdd(&stats[c + 128],  s2[c]);
    }
}

__global__ void bn_apply(float* __restrict__ h, const float* __restrict__ stats,
                         const float* __restrict__ g, const float* __restrict__ b)
{
    int idx = blockIdx.x * 256 + threadIdx.x;
    if (idx >= NN * 128) return;
    int c = idx & 127;
    float mu  = stats[c] * (1.0f / NN);
    float var = stats[c + 128] * (1.0f / NN) - mu * mu;
    h[idx] = (h[idx] - mu) * rsqrtf(var + LN_EPS) * g[c] + b[c];
}

// ---------------------------------------------------------------- launcher
extern "C" void kernel_launch(void* const* d_in, const int* in_sizes, int n_in,
                              void* d_out, int out_size, void* d_ws, size_t ws_size,
                              hipStream_t stream)
{
    auto F = [&](int i) { return (const float*)d_in[i]; };
    const float* x  = F(0);
    const int*   ei = (const int*)d_in[1];
    const float* bn_g = F(23);
    const float* bn_b = F(24);
    // per-conv params: base = 2 + 7*i : ln_g, ln_b, sw, sb, bw, bb, bias

    // ---- workspace layout
    short* wtf0 = (short*)d_ws;                 // 81920 shorts
    short* wtf1 = wtf0 + 81920;                 // 81920
    short* wtf2 = wtf1 + 81920;                 // 92160
    short* hwb  = wtf2 + 92160;                 // NN*128 bf16 (NN*40 for conv2)
    float* dis  = (float*)(hwb + 6400000);      // NN
    float* h1   = dis + 50000;                  // NN*128
    float* h2   = h1  + 6400000;
    float* stats = h2 + 6400000;                // 256
    int*   degi = (int*)(stats + 256);          // NN
    int*   off  = degi + 50000;                 // NN+1
    int*   cur  = off + 50001;                  // NN
    int*   rows = cur + 50000;                  // NE
    float* outf = (float*)d_out;

    // ---- degree -> dis, CSR build
    (void)hipMemsetAsync(degi, 0, 50000 * sizeof(int), stream);
    (void)hipMemsetAsync(cur,  0, 50000 * sizeof(int), stream);
    degi_kernel<<<(NE + 255) / 256, 256, 0, stream>>>(ei + NE, degi);
    dis_kernel<<<(NN + 255) / 256, 256, 0, stream>>>(degi, dis);
    scan_kernel<<<1, 1024, 0, stream>>>(degi, off);
    csr_fill<<<(NE + 255) / 256, 256, 0, stream>>>(ei, off, cur, rows);

    // ---- pack B fragments (bf16)
    pack_frag<<<(81920 + 255) / 256, 256, 0, stream>>>(F(4),  F(6),  wtf0, 128, 8, 128, 81920);
    pack_frag<<<(81920 + 255) / 256, 256, 0, stream>>>(F(11), F(13), wtf1, 128, 8, 128, 81920);
    pack_frag<<<(92160 + 255) / 256, 256, 0, stream>>>(F(18), F(20), wtf2, 384, 3, 40,  92160);

    const int gridN64 = (NN + 63) / 64;         // 782
    const int gridN32 = (NN + 31) / 32;         // 1563
    const int gridNF  = (NN * 128 + 255) / 256;

    // ---- conv0: x -> h1
    fkan_reg<128, 128, 8, 20, 64><<<gridN64, 256, 0, stream>>>(x, nullptr, nullptr,
        F(2), F(3), wtf0, F(5), F(7), hwb);
    agg_gather_bf16<128><<<NN, 64, 0, stream>>>(off, rows, dis, hwb, F(8), h1);
    (void)hipMemsetAsync(stats, 0, 256 * sizeof(float), stream);
    bn_stats<<<256, 256, 0, stream>>>(h1, stats);
    bn_apply<<<gridNF, 256, 0, stream>>>(h1, stats, bn_g, bn_b);

    // ---- conv1: h1 -> h2
    fkan_reg<128, 128, 8, 20, 64><<<gridN64, 256, 0, stream>>>(h1, nullptr, nullptr,
        F(9), F(10), wtf1, F(12), F(14), hwb);
    agg_gather_bf16<128><<<NN, 64, 0, stream>>>(off, rows, dis, hwb, F(15), h2);
    (void)hipMemsetAsync(stats, 0, 256 * sizeof(float), stream);
    bn_stats<<<256, 256, 0, stream>>>(h2, stats);
    bn_apply<<<gridNF, 256, 0, stream>>>(h2, stats, bn_g, bn_b);

    // ---- conv2: [x|h1|h2] -> d_out
    fkan_reg<384, 40, 3, 60, 32><<<gridN32, 128, 0, stream>>>(x, h1, h2,
        F(16), F(17), wtf2, F(19), F(21), hwb);
    agg_gather_bf16<40><<<NN, 64, 0, stream>>>(off, rows, dis, hwb, F(22), outf);
}

// Round 7
// 680.613 us; speedup vs baseline: 1.0014x; 1.0014x over previous
//
#include <hip/hip_runtime.h>
#include <math.h>

constexpr int NN = 50000;
constexpr int NE = 1600000;
constexpr float LN_EPS = 1e-5f;

constexpr int NBKT  = 8;                       // coarse dst buckets
constexpr int SPAN  = NN / NBKT;               // 6250 nodes per bucket
constexpr int CHUNK = 8192;                    // edges per pass-1 block
constexpr int NB1   = (NE + CHUNK - 1) / CHUNK;  // 196

typedef __attribute__((ext_vector_type(8))) short short8;
typedef __attribute__((ext_vector_type(4))) float f32x4;

__device__ __forceinline__ short f2bf(float f)
{
    unsigned u = __builtin_bit_cast(unsigned, f);
    u += 0x7fffu + ((u >> 16) & 1u);          // RNE
    return (short)(u >> 16);
}

__device__ __forceinline__ float2 bf2x2(unsigned p)
{
    float2 r;
    r.x = __builtin_bit_cast(float, p << 16);          // low ushort
    r.y = __builtin_bit_cast(float, p & 0xffff0000u);  // high ushort
    return r;
}

// ---------------------------------------------------------------- pass 0: degree + bucket histogram
__global__ __launch_bounds__(256) void csr_hist(const int* __restrict__ col,
                                                int* __restrict__ degi,
                                                int* __restrict__ histo)
{
    __shared__ int hcnt[NBKT];
    const int tid = threadIdx.x;
    if (tid < NBKT) hcnt[tid] = 0;
    __syncthreads();
    const int e0 = blockIdx.x * CHUNK;
    const int e1 = min(e0 + CHUNK, NE);
    for (int e = e0 + tid; e < e1; e += 256) {
        int c = col[e];
        atomicAdd(&degi[c], 1);
        atomicAdd(&hcnt[(unsigned)c / (unsigned)SPAN], 1);
    }
    __syncthreads();
    if (tid < NBKT) histo[tid * NB1 + blockIdx.x] = hcnt[tid];
}

// ---------------------------------------------------------------- scan of 8*NB1 chunk counts
__global__ __launch_bounds__(256) void csr_scan2(int* __restrict__ histo)
{
    constexpr int M = NBKT * NB1;              // 1568
    constexpr int T = (M + 255) / 256;         // 7
    __shared__ int part[256];
    const int t = threadIdx.x;
    int v[T];
    int s = 0;
    #pragma unroll
    for (int j = 0; j < T; ++j) {
        int i = t * T + j;
        v[j] = (i < M) ? histo[i] : 0;
        s += v[j];
    }
    part[t] = s;
    __syncthreads();
    for (int d = 1; d < 256; d <<= 1) {
        int add = (t >= d) ? part[t - d] : 0;
        __syncthreads();
        part[t] += add;
        __syncthreads();
    }
    int run = part[t] - s;
    #pragma unroll
    for (int j = 0; j < T; ++j) {
        int i = t * T + j;
        if (i < M) { histo[i] = run; run += v[j]; }
    }
}

// ---------------------------------------------------------------- pass 1: partition into buckets
__global__ __launch_bounds__(256) void csr_part(const int* __restrict__ ei,
                                                const int* __restrict__ histo,
                                                uint2* __restrict__ staging)
{
    __shared__ int lcur[NBKT];
    const int tid = threadIdx.x;
    if (tid < NBKT) lcur[tid] = histo[tid * NB1 + blockIdx.x];
    __syncthreads();
    const int e0 = blockIdx.x * CHUNK;
    const int e1 = min(e0 + CHUNK, NE);
    for (int e = e0 + tid; e < e1; e += 256) {
        int r = ei[e];
        int c = ei[NE + e];
        int slot = atomicAdd(&lcur[(unsigned)c / (unsigned)SPAN], 1);
        staging[slot] = make_uint2((unsigned)r, (unsigned)c);
    }
}

// ---------------------------------------------------------------- pass 2: bucket-local scatter
// bucket = blockIdx & 7 -> all blocks of a bucket land on one XCD (round-robin heuristic)
template<int PB2>
__global__ __launch_bounds__(256) void csr_scatter(const uint2* __restrict__ staging,
                                                   const int* __restrict__ off,
                                                   int* __restrict__ cur,
                                                   int* __restrict__ rows)
{
    const int b   = blockIdx.x & (NBKT - 1);
    const int blk = blockIdx.x >> 3;
    const int base = off[b * SPAN];
    const int end  = off[(b + 1) * SPAN];
    for (int i = base + blk * 256 + threadIdx.x; i < end; i += PB2 * 256) {
        uint2 e = staging[i];
        int p = off[e.y] + atomicAdd(&cur[e.y], 1);
        rows[p] = (int)e.x;
    }
}

// ---------------------------------------------------------------- dis
__global__ void dis_kernel(const int* __restrict__ degi, float* __restrict__ dis)
{
    int i = blockIdx.x * 256 + threadIdx.x;
    if (i < NN) dis[i] = rsqrtf((float)degi[i] + 1.0f);   // +1 = self loop
}

// ---------------------------------------------------------------- exclusive scan (single block)
__global__ __launch_bounds__(1024) void scan_kernel(const int* __restrict__ deg,
                                                    int* __restrict__ off)
{
    __shared__ int part[1024];
    const int t = threadIdx.x;
    constexpr int CH = (NN + 1023) / 1024;     // 49
    const int base = t * CH;
    int s = 0;
    for (int j = 0; j < CH; ++j) { int i = base + j; if (i < NN) s += deg[i]; }
    part[t] = s;
    __syncthreads();
    for (int d = 1; d < 1024; d <<= 1) {
        int add = (t >= d) ? part[t - d] : 0;
        __syncthreads();
        part[t] += add;
        __syncthreads();
    }
    int run = part[t] - s;
    for (int j = 0; j < CH; ++j) {
        int i = base + j;
        if (i < NN) { off[i] = run; run += deg[i]; }
    }
    if (t == 1023) off[NN] = part[1023];
}

// ---------------------------------------------------------------- B-fragment pack
// wtf[((kk*OT + ot)*64 + lane)*8 + j8]:
//   g4 = lane>>4; s = kk*8 + j8; f = g4*(D/4) + s/5; g5 = s%5; o = ot*16 + (lane&15)
__global__ void pack_frag(const float* __restrict__ sw, const float* __restrict__ bw,
                          short* __restrict__ wtf, int D, int OT, int DO, int total)
{
    int idx = blockIdx.x * 256 + threadIdx.x;
    if (idx >= total) return;
    int j8   = idx & 7;
    int lane = (idx >> 3) & 63;
    int rest = idx >> 9;               // kk*OT + ot
    int ot = rest % OT, kk = rest / OT;
    int g4 = lane >> 4;
    int s  = kk * 8 + j8;
    int f  = g4 * (D / 4) + s / 5;
    int g5 = s % 5;
    int o  = ot * 16 + (lane & 15);
    float val = 0.f;
    if (o < DO) val = (g5 < 4) ? sw[o * D * 4 + f * 4 + g5] : bw[o * D + f];
    wtf[idx] = f2bf(val);
}

// ---------------------------------------------------------------- FastKAN layer (register-A MFMA)
template<int D, int DO, int OT, int KKC, int NODES>
__global__ __launch_bounds__(NODES * 4) void fkan_reg(
    const float* __restrict__ s0, const float* __restrict__ s1, const float* __restrict__ s2,
    const float* __restrict__ ln_g, const float* __restrict__ ln_b,
    const short* __restrict__ wtf, const float* __restrict__ sb, const float* __restrict__ bb,
    short* __restrict__ out)
{
    constexpr int BW  = D / 4;         // features per g4-block
    constexpr int GBS = BW + 1;        // g4-block stride (u32)
    constexpr int RS  = 4 * GBS + 1;   // node row stride (u32)
    __shared__ unsigned pkL[NODES * RS];

    const int tid = threadIdx.x;

    // ---- phase A: LN + silu, packed into LDS
    {
        const int anode = tid >> 2, q = tid & 3;
        const int gnode = blockIdx.x * NODES + anode;
        const int snode = (gnode < NN) ? gnode : (NN - 1);
        unsigned* prow = &pkL[anode * RS + q * GBS];
        float sum = 0.f, sq = 0.f;
        #pragma unroll
        for (int i4 = 0; i4 < BW / 4; ++i4) {
            int f = q * BW + i4 * 4;
            const float* src = (D == 128) ? s0 : ((f < 128) ? s0 : (f < 256) ? s1 : s2);
            float4 v = *(const float4*)&src[snode * 128 + (f & 127)];
            sum += (v.x + v.y) + (v.z + v.w);
            sq  += (v.x * v.x + v.y * v.y) + (v.z * v.z + v.w * v.w);
            prow[i4 * 4 + 0] = __builtin_bit_cast(unsigned, v.x);
            prow[i4 * 4 + 1] = __builtin_bit_cast(unsigned, v.y);
            prow[i4 * 4 + 2] = __builtin_bit_cast(unsigned, v.z);
            prow[i4 * 4 + 3] = __builtin_bit_cast(unsigned, v.w);
        }
        sum += __shfl_xor(sum, 1); sum += __shfl_xor(sum, 2);
        sq  += __shfl_xor(sq, 1);  sq  += __shfl_xor(sq, 2);
        float mu   = sum * (1.0f / D);
        float var  = sq * (1.0f / D) - mu * mu;
        float rstd = rsqrtf(var + LN_EPS);
        #pragma unroll 4
        for (int i = 0; i < BW; ++i) {
            int f = q * BW + i;
            float v  = __builtin_bit_cast(float, prow[i]);
            float hn = (v - mu) * rstd * ln_g[f] + ln_b[f];
            float sl = v / (1.0f + __expf(-v));
            prow[i] = ((unsigned)(unsigned short)f2bf(hn) << 16)
                    | ((unsigned)(unsigned short)f2bf(sl) & 0xffffu);
        }
    }
    __syncthreads();

    // ---- phase 2: register-A MFMA
    const int wv = tid >> 6, lane = tid & 63;
    const int m = lane & 15, g4 = lane >> 4;
    const unsigned* pkb = &pkL[(wv * 16 + m) * RS + g4 * GBS];

    f32x4 acc[OT];
    #pragma unroll
    for (int ot = 0; ot < OT; ++ot) acc[ot] = f32x4{0.f, 0.f, 0.f, 0.f};

    union AU { unsigned u[4]; short8 s; };

    for (int per = 0; per < KKC / 5; ++per) {          // 5 kk = 40 slots = 8 features
        const unsigned* pp = pkb + per * 8;
        const short* bp = wtf + ((per * 5) * OT * 512) + lane * 8;
        #pragma unroll
        for (int c = 0; c < 5; ++c) {
            unsigned p[3];
            float h75[3];
            constexpr int FL0[5] = {0, 1, 3, 4, 6};
            constexpr int NF[5]  = {2, 3, 2, 3, 2};
            #pragma unroll
            for (int i = 0; i < 3; ++i) {
                if (i < NF[c]) {
                    p[i] = pp[FL0[c] + i];
                    h75[i] = __builtin_bit_cast(float, p[i] & 0xffff0000u) * 0.75f;
                }
            }
            AU a;
            #pragma unroll
            for (int i = 0; i < 4; ++i) {
                unsigned v2[2];
                #pragma unroll
                for (int h = 0; h < 2; ++h) {
                    int sl = c * 8 + 2 * i + h;        // compile-time
                    int fl = sl / 5 - FL0[c];
                    int g  = sl % 5;
                    if (g == 4) {
                        v2[h] = p[fl] & 0xffffu;
                    } else {
                        float t = h75[fl] + (1.5f - (float)g);
                        float e = __expf(-t * t);
                        v2[h] = (unsigned)(unsigned short)f2bf(e);
                    }
                }
                a.u[i] = (v2[0] & 0xffffu) | (v2[1] << 16);
            }
            #pragma unroll
            for (int ot = 0; ot < OT; ++ot) {
                short8 b = *(const short8*)(bp + (c * OT + ot) * 512);
                acc[ot] = __builtin_amdgcn_mfma_f32_16x16x32_bf16(a.s, b, acc[ot], 0, 0, 0);
            }
        }
    }

    // ---- epilogue: bf16 write, C/D: col=lane&15, row=(lane>>4)*4+reg
    const int nrow0 = blockIdx.x * NODES + wv * 16 + g4 * 4;
    #pragma unroll
    for (int ot = 0; ot < OT; ++ot) {
        int o = ot * 16 + m;
        if (o < DO) {
            float cb = sb[o] + bb[o];
            #pragma unroll
            for (int r = 0; r < 4; ++r) {
                int nr = nrow0 + r;
                if (nr < NN) out[nr * DO + o] = f2bf(acc[ot][r] + cb);
            }
        }
    }
}

// ---------------------------------------------------------------- CSR gather (bf16 rows)
template<int DO>
__global__ __launch_bounds__(64) void agg_gather_bf16(
    const int* __restrict__ off, const int* __restrict__ rows,
    const float* __restrict__ dis, const short* __restrict__ hwb,
    const float* __restrict__ bias, float* __restrict__ out)
{
    constexpr int ACT = DO / 2;        // active compute lanes
    const int n   = blockIdx.x;
    const int tid = threadIdx.x;
    __shared__ int   srow[64];
    __shared__ float swgt[64];

    const int e0 = off[n], e1 = off[n + 1];
    const float dn = dis[n];
    float ax = 0.f, ay = 0.f;
    if (tid < ACT) {
        unsigned p = *(const unsigned*)&hwb[n * DO + 2 * tid];
        float2 v = bf2x2(p);
        ax = dn * dn * v.x + bias[2 * tid];
        ay = dn * dn * v.y + bias[2 * tid + 1];
    }

    for (int t0 = e0; t0 < e1; t0 += 64) {
        const int nt = min(64, e1 - t0);
        if (tid < nt) {
            int r = rows[t0 + tid];
            srow[tid] = r;
            swgt[tid] = dn * dis[r];
        }
        __syncthreads();
        if (tid < ACT) {
            #pragma unroll 4
            for (int j = 0; j < nt; ++j) {
                unsigned p = *(const unsigned*)&hwb[srow[j] * DO + 2 * tid];
                float2 v = bf2x2(p);
                float w = swgt[j];
                ax += w * v.x;
                ay += w * v.y;
            }
        }
        __syncthreads();
    }
    if (tid < ACT) {
        out[n * DO + 2 * tid]     = ax;
        out[n * DO + 2 * tid + 1] = ay;
    }
}

// ---------------------------------------------------------------- batchnorm
__global__ void bn_stats(const float* __restrict__ h, float* __restrict__ stats)
{
    __shared__ float s1[256], s2[256];
    int c = threadIdx.x & 127;
    int half = threadIdx.x >> 7;
    float sum = 0.f, sq = 0.f;
    for (int n = blockIdx.x * 2 + half; n < NN; n += 512) {
        float v = h[n * 128 + c];
        sum += v; sq += v * v;
    }
    s1[threadIdx.x] = sum; s2[threadIdx.x] = sq;
    __syncthreads();
    if (half == 0) {
        s1[c] += s1[c + 128]; s2[c] += s2[c + 128];
        atomicAdd(&stats[c],        s1[c]);
        atomicAdd(&stats[c + 128],  s2[c]);
    }
}

__global__ void bn_apply(float* __restrict__ h, const float* __restrict__ stats,
                         const float* __restrict__ g, const float* __restrict__ b)
{
    int idx = blockIdx.x * 256 + threadIdx.x;
    if (idx >= NN * 128) return;
    int c = idx & 127;
    float mu  = stats[c] * (1.0f / NN);
    float var = stats[c + 128] * (1.0f / NN) - mu * mu;
    h[idx] = (h[idx] - mu) * rsqrtf(var + LN_EPS) * g[c] + b[c];
}

// ---------------------------------------------------------------- launcher
extern "C" void kernel_launch(void* const* d_in, const int* in_sizes, int n_in,
                              void* d_out, int out_size, void* d_ws, size_t ws_size,
                              hipStream_t stream)
{
    auto F = [&](int i) { return (const float*)d_in[i]; };
    const float* x  = F(0);
    const int*   ei = (const int*)d_in[1];
    const float* bn_g = F(23);
    const float* bn_b = F(24);
    // per-conv params: base = 2 + 7*i : ln_g, ln_b, sw, sb, bw, bb, bias

    // ---- workspace layout
    short* wtf0 = (short*)d_ws;                 // 81920 shorts
    short* wtf1 = wtf0 + 81920;                 // 81920
    short* wtf2 = wtf1 + 81920;                 // 92160
    short* hwb  = wtf2 + 92160;                 // NN*128 bf16 (NN*40 for conv2)
    float* dis  = (float*)(hwb + 6400000);      // NN
    float* h1   = dis + 50000;                  // NN*128
    float* h2   = h1  + 6400000;
    float* stats = h2 + 6400000;                // 256
    int*   degi = (int*)(stats + 256);          // NN
    int*   off  = degi + 50000;                 // NN+1
    int*   cur  = off + 50001;                  // NN
    int*   rows = cur + 50000;                  // NE
    int*   histo = rows + NE;                   // 8*NB1 = 1568
    uint2* staging = (uint2*)h1;                // 12.8 MB, dead until conv0 output
    float* outf = (float*)d_out;

    // ---- CSR build: hist(+degree) -> scans -> partition -> bucket-local scatter
    (void)hipMemsetAsync(degi, 0, 50000 * sizeof(int), stream);
    (void)hipMemsetAsync(cur,  0, 50000 * sizeof(int), stream);
    csr_hist<<<NB1, 256, 0, stream>>>(ei + NE, degi, histo);
    dis_kernel<<<(NN + 255) / 256, 256, 0, stream>>>(degi, dis);
    scan_kernel<<<1, 1024, 0, stream>>>(degi, off);
    csr_scan2<<<1, 256, 0, stream>>>(histo);
    csr_part<<<NB1, 256, 0, stream>>>(ei, histo, staging);
    csr_scatter<128><<<128 * NBKT, 256, 0, stream>>>(staging, off, cur, rows);

    // ---- pack B fragments (bf16)
    pack_frag<<<(81920 + 255) / 256, 256, 0, stream>>>(F(4),  F(6),  wtf0, 128, 8, 128, 81920);
    pack_frag<<<(81920 + 255) / 256, 256, 0, stream>>>(F(11), F(13), wtf1, 128, 8, 128, 81920);
    pack_frag<<<(92160 + 255) / 256, 256, 0, stream>>>(F(18), F(20), wtf2, 384, 3, 40,  92160);

    const int gridN64 = (NN + 63) / 64;         // 782
    const int gridN32 = (NN + 31) / 32;         // 1563
    const int gridNF  = (NN * 128 + 255) / 256;

    // ---- conv0: x -> h1
    fkan_reg<128, 128, 8, 20, 64><<<gridN64, 256, 0, stream>>>(x, nullptr, nullptr,
        F(2), F(3), wtf0, F(5), F(7), hwb);
    agg_gather_bf16<128><<<NN, 64, 0, stream>>>(off, rows, dis, hwb, F(8), h1);
    (void)hipMemsetAsync(stats, 0, 256 * sizeof(float), stream);
    bn_stats<<<256, 256, 0, stream>>>(h1, stats);
    bn_apply<<<gridNF, 256, 0, stream>>>(h1, stats, bn_g, bn_b);

    // ---- conv1: h1 -> h2
    fkan_reg<128, 128, 8, 20, 64><<<gridN64, 256, 0, stream>>>(h1, nullptr, nullptr,
        F(9), F(10), wtf1, F(12), F(14), hwb);
    agg_gather_bf16<128><<<NN, 64, 0, stream>>>(off, rows, dis, hwb, F(15), h2);
    (void)hipMemsetAsync(stats, 0, 256 * sizeof(float), stream);
    bn_stats<<<256, 256, 0, stream>>>(h2, stats);
    bn_apply<<<gridNF, 256, 0, stream>>>(h2, stats, bn_g, bn_b);

    // ---- conv2: [x|h1|h2] -> d_out
    fkan_reg<384, 40, 3, 60, 32><<<gridN32, 128, 0, stream>>>(x, h1, h2,
        F(16), F(17), wtf2, F(19), F(21), hwb);
    agg_gather_bf16<40><<<NN, 64, 0, stream>>>(off, rows, dis, hwb, F(22), outf);
}

// Round 8
// 595.635 us; speedup vs baseline: 1.1442x; 1.1427x over previous
//
#include <hip/hip_runtime.h>
#include <math.h>

constexpr int NN = 50000;
constexpr int NE = 1600000;
constexpr float LN_EPS = 1e-5f;

constexpr int NBKT  = 8;                       // coarse dst buckets
constexpr int SPAN  = NN / NBKT;               // 6250 nodes per bucket
constexpr int CHUNK = 8192;                    // edges per pass-1 block
constexpr int NB1   = (NE + CHUNK - 1) / CHUNK;  // 196
constexpr int NSB   = (NN + 255) / 256;        // 196 scan blocks

typedef __attribute__((ext_vector_type(8))) short short8;
typedef __attribute__((ext_vector_type(4))) float f32x4;

__device__ __forceinline__ short f2bf(float f)
{
    unsigned u = __builtin_bit_cast(unsigned, f);
    u += 0x7fffu + ((u >> 16) & 1u);          // RNE
    return (short)(u >> 16);
}

__device__ __forceinline__ float2 bf2x2(unsigned p)
{
    float2 r;
    r.x = __builtin_bit_cast(float, p << 16);          // low ushort
    r.y = __builtin_bit_cast(float, p & 0xffff0000u);  // high ushort
    return r;
}

// ---------------------------------------------------------------- pass 0: degree + bucket histogram
__global__ __launch_bounds__(256) void csr_hist(const int* __restrict__ col,
                                                int* __restrict__ degi,
                                                int* __restrict__ histo)
{
    __shared__ int hcnt[NBKT];
    const int tid = threadIdx.x;
    if (tid < NBKT) hcnt[tid] = 0;
    __syncthreads();
    const int e0 = blockIdx.x * CHUNK;
    const int e1 = min(e0 + CHUNK, NE);
    for (int e = e0 + tid; e < e1; e += 256) {
        int c = col[e];
        atomicAdd(&degi[c], 1);
        atomicAdd(&hcnt[(unsigned)c / (unsigned)SPAN], 1);
    }
    __syncthreads();
    if (tid < NBKT) histo[tid * NB1 + blockIdx.x] = hcnt[tid];
}

// ---------------------------------------------------------------- scan of 8*NB1 chunk counts
__global__ __launch_bounds__(256) void csr_scan2(int* __restrict__ histo)
{
    constexpr int M = NBKT * NB1;              // 1568
    constexpr int T = (M + 255) / 256;         // 7
    __shared__ int part[256];
    const int t = threadIdx.x;
    int v[T];
    int s = 0;
    #pragma unroll
    for (int j = 0; j < T; ++j) {
        int i = t * T + j;
        v[j] = (i < M) ? histo[i] : 0;
        s += v[j];
    }
    part[t] = s;
    __syncthreads();
    for (int d = 1; d < 256; d <<= 1) {
        int add = (t >= d) ? part[t - d] : 0;
        __syncthreads();
        part[t] += add;
        __syncthreads();
    }
    int run = part[t] - s;
    #pragma unroll
    for (int j = 0; j < T; ++j) {
        int i = t * T + j;
        if (i < M) { histo[i] = run; run += v[j]; }
    }
}

// ---------------------------------------------------------------- pass 1: partition into buckets
__global__ __launch_bounds__(256) void csr_part(const int* __restrict__ ei,
                                                const int* __restrict__ histo,
                                                uint2* __restrict__ staging)
{
    __shared__ int lcur[NBKT];
    const int tid = threadIdx.x;
    if (tid < NBKT) lcur[tid] = histo[tid * NB1 + blockIdx.x];
    __syncthreads();
    const int e0 = blockIdx.x * CHUNK;
    const int e1 = min(e0 + CHUNK, NE);
    for (int e = e0 + tid; e < e1; e += 256) {
        int r = ei[e];
        int c = ei[NE + e];
        int slot = atomicAdd(&lcur[(unsigned)c / (unsigned)SPAN], 1);
        staging[slot] = make_uint2((unsigned)r, (unsigned)c);
    }
}

// ---------------------------------------------------------------- pass 2: bucket-local scatter
template<int PB2>
__global__ __launch_bounds__(256) void csr_scatter(const uint2* __restrict__ staging,
                                                   const int* __restrict__ off,
                                                   int* __restrict__ cur,
                                                   int* __restrict__ rows)
{
    const int b   = blockIdx.x & (NBKT - 1);
    const int blk = blockIdx.x >> 3;
    const int base = off[b * SPAN];
    const int end  = off[(b + 1) * SPAN];
    for (int i = base + blk * 256 + threadIdx.x; i < end; i += PB2 * 256) {
        uint2 e = staging[i];
        int p = off[e.y] + atomicAdd(&cur[e.y], 1);
        rows[p] = (int)e.x;
    }
}

// ---------------------------------------------------------------- dis
__global__ void dis_kernel(const int* __restrict__ degi, float* __restrict__ dis)
{
    int i = blockIdx.x * 256 + threadIdx.x;
    if (i < NN) dis[i] = rsqrtf((float)degi[i] + 1.0f);   // +1 = self loop
}

// ---------------------------------------------------------------- hierarchical degree scan
__global__ __launch_bounds__(256) void scan_p1(const int* __restrict__ deg,
                                               int* __restrict__ off,
                                               int* __restrict__ partials)
{
    __shared__ int sh[256];
    const int t = threadIdx.x;
    const int i = blockIdx.x * 256 + t;
    int v = (i < NN) ? deg[i] : 0;
    sh[t] = v;
    __syncthreads();
    for (int d = 1; d < 256; d <<= 1) {
        int add = (t >= d) ? sh[t - d] : 0;
        __syncthreads();
        sh[t] += add;
        __syncthreads();
    }
    if (i < NN) off[i] = sh[t] - v;            // local exclusive
    if (t == 255) partials[blockIdx.x] = sh[255];
}

__global__ __launch_bounds__(256) void scan_p2(int* __restrict__ partials)
{
    __shared__ int sh[256];
    const int t = threadIdx.x;
    int v = (t < NSB) ? partials[t] : 0;
    sh[t] = v;
    __syncthreads();
    for (int d = 1; d < 256; d <<= 1) {
        int add = (t >= d) ? sh[t - d] : 0;
        __syncthreads();
        sh[t] += add;
        __syncthreads();
    }
    if (t < NSB) partials[t] = sh[t] - v;      // exclusive
    if (t == 255) partials[NSB] = sh[255];     // total
}

__global__ __launch_bounds__(256) void scan_p3(int* __restrict__ off,
                                               const int* __restrict__ partials)
{
    const int i = blockIdx.x * 256 + threadIdx.x;
    if (i < NN) off[i] += partials[blockIdx.x];
    if (i == 0) off[NN] = partials[NSB];
}

// ---------------------------------------------------------------- B-fragment pack
// wtf[((kk*OT + ot)*64 + lane)*8 + j8]:
//   g4 = lane>>4; s = kk*8 + j8; f = g4*(D/4) + s/5; g5 = s%5; o = ot*16 + (lane&15)
__global__ void pack_frag(const float* __restrict__ sw, const float* __restrict__ bw,
                          short* __restrict__ wtf, int D, int OT, int DO, int total)
{
    int idx = blockIdx.x * 256 + threadIdx.x;
    if (idx >= total) return;
    int j8   = idx & 7;
    int lane = (idx >> 3) & 63;
    int rest = idx >> 9;               // kk*OT + ot
    int ot = rest % OT, kk = rest / OT;
    int g4 = lane >> 4;
    int s  = kk * 8 + j8;
    int f  = g4 * (D / 4) + s / 5;
    int g5 = s % 5;
    int o  = ot * 16 + (lane & 15);
    float val = 0.f;
    if (o < DO) val = (g5 < 4) ? sw[o * D * 4 + f * 4 + g5] : bw[o * D + f];
    wtf[idx] = f2bf(val);
}

// ---------------------------------------------------------------- FastKAN layer (register-A MFMA)
template<int D, int DO, int OT, int KKC, int NODES>
__global__ __launch_bounds__(NODES * 4) void fkan_reg(
    const float* __restrict__ s0, const float* __restrict__ s1, const float* __restrict__ s2,
    const float* __restrict__ ln_g, const float* __restrict__ ln_b,
    const short* __restrict__ wtf, const float* __restrict__ sb, const float* __restrict__ bb,
    short* __restrict__ out)
{
    constexpr int BW  = D / 4;         // features per g4-block
    constexpr int GBS = BW + 1;        // g4-block stride (u32)
    constexpr int RS  = 4 * GBS + 1;   // node row stride (u32)
    __shared__ unsigned pkL[NODES * RS];

    const int tid = threadIdx.x;

    // ---- phase A: LN + silu, packed into LDS
    {
        const int anode = tid >> 2, q = tid & 3;
        const int gnode = blockIdx.x * NODES + anode;
        const int snode = (gnode < NN) ? gnode : (NN - 1);
        unsigned* prow = &pkL[anode * RS + q * GBS];
        float sum = 0.f, sq = 0.f;
        #pragma unroll
        for (int i4 = 0; i4 < BW / 4; ++i4) {
            int f = q * BW + i4 * 4;
            const float* src = (D == 128) ? s0 : ((f < 128) ? s0 : (f < 256) ? s1 : s2);
            float4 v = *(const float4*)&src[snode * 128 + (f & 127)];
            sum += (v.x + v.y) + (v.z + v.w);
            sq  += (v.x * v.x + v.y * v.y) + (v.z * v.z + v.w * v.w);
            prow[i4 * 4 + 0] = __builtin_bit_cast(unsigned, v.x);
            prow[i4 * 4 + 1] = __builtin_bit_cast(unsigned, v.y);
            prow[i4 * 4 + 2] = __builtin_bit_cast(unsigned, v.z);
            prow[i4 * 4 + 3] = __builtin_bit_cast(unsigned, v.w);
        }
        sum += __shfl_xor(sum, 1); sum += __shfl_xor(sum, 2);
        sq  += __shfl_xor(sq, 1);  sq  += __shfl_xor(sq, 2);
        float mu   = sum * (1.0f / D);
        float var  = sq * (1.0f / D) - mu * mu;
        float rstd = rsqrtf(var + LN_EPS);
        #pragma unroll 4
        for (int i = 0; i < BW; ++i) {
            int f = q * BW + i;
            float v  = __builtin_bit_cast(float, prow[i]);
            float hn = (v - mu) * rstd * ln_g[f] + ln_b[f];
            float sl = v / (1.0f + __expf(-v));
            prow[i] = ((unsigned)(unsigned short)f2bf(hn) << 16)
                    | ((unsigned)(unsigned short)f2bf(sl) & 0xffffu);
        }
    }
    __syncthreads();

    // ---- phase 2: register-A MFMA
    const int wv = tid >> 6, lane = tid & 63;
    const int m = lane & 15, g4 = lane >> 4;
    const unsigned* pkb = &pkL[(wv * 16 + m) * RS + g4 * GBS];

    f32x4 acc[OT];
    #pragma unroll
    for (int ot = 0; ot < OT; ++ot) acc[ot] = f32x4{0.f, 0.f, 0.f, 0.f};

    union AU { unsigned u[4]; short8 s; };

    for (int per = 0; per < KKC / 5; ++per) {          // 5 kk = 40 slots = 8 features
        const unsigned* pp = pkb + per * 8;
        const short* bp = wtf + ((per * 5) * OT * 512) + lane * 8;
        #pragma unroll
        for (int c = 0; c < 5; ++c) {
            unsigned p[3];
            float h75[3];
            constexpr int FL0[5] = {0, 1, 3, 4, 6};
            constexpr int NF[5]  = {2, 3, 2, 3, 2};
            #pragma unroll
            for (int i = 0; i < 3; ++i) {
                if (i < NF[c]) {
                    p[i] = pp[FL0[c] + i];
                    h75[i] = __builtin_bit_cast(float, p[i] & 0xffff0000u) * 0.75f;
                }
            }
            AU a;
            #pragma unroll
            for (int i = 0; i < 4; ++i) {
                unsigned v2[2];
                #pragma unroll
                for (int h = 0; h < 2; ++h) {
                    int sl = c * 8 + 2 * i + h;        // compile-time
                    int fl = sl / 5 - FL0[c];
                    int g  = sl % 5;
                    if (g == 4) {
                        v2[h] = p[fl] & 0xffffu;
                    } else {
                        float t = h75[fl] + (1.5f - (float)g);
                        float e = __expf(-t * t);
                        v2[h] = (unsigned)(unsigned short)f2bf(e);
                    }
                }
                a.u[i] = (v2[0] & 0xffffu) | (v2[1] << 16);
            }
            #pragma unroll
            for (int ot = 0; ot < OT; ++ot) {
                short8 b = *(const short8*)(bp + (c * OT + ot) * 512);
                acc[ot] = __builtin_amdgcn_mfma_f32_16x16x32_bf16(a.s, b, acc[ot], 0, 0, 0);
            }
        }
    }

    // ---- epilogue: bf16 write, C/D: col=lane&15, row=(lane>>4)*4+reg
    const int nrow0 = blockIdx.x * NODES + wv * 16 + g4 * 4;
    #pragma unroll
    for (int ot = 0; ot < OT; ++ot) {
        int o = ot * 16 + m;
        if (o < DO) {
            float cb = sb[o] + bb[o];
            #pragma unroll
            for (int r = 0; r < 4; ++r) {
                int nr = nrow0 + r;
                if (nr < NN) out[nr * DO + o] = f2bf(acc[ot][r] + cb);
            }
        }
    }
}

// ---------------------------------------------------------------- CSR gather (bf16 rows)
template<int DO>
__global__ __launch_bounds__(64) void agg_gather_bf16(
    const int* __restrict__ off, const int* __restrict__ rows,
    const float* __restrict__ dis, const short* __restrict__ hwb,
    const float* __restrict__ bias, float* __restrict__ out)
{
    constexpr int ACT = DO / 2;        // active compute lanes
    const int n   = blockIdx.x;
    const int tid = threadIdx.x;
    __shared__ int   srow[64];
    __shared__ float swgt[64];

    const int e0 = off[n], e1 = off[n + 1];
    const float dn = dis[n];
    float ax = 0.f, ay = 0.f;
    if (tid < ACT) {
        unsigned p = *(const unsigned*)&hwb[n * DO + 2 * tid];
        float2 v = bf2x2(p);
        ax = dn * dn * v.x + bias[2 * tid];
        ay = dn * dn * v.y + bias[2 * tid + 1];
    }

    for (int t0 = e0; t0 < e1; t0 += 64) {
        const int nt = min(64, e1 - t0);
        if (tid < nt) {
            int r = rows[t0 + tid];
            srow[tid] = r;
            swgt[tid] = dn * dis[r];
        }
        __syncthreads();
        if (tid < ACT) {
            #pragma unroll 4
            for (int j = 0; j < nt; ++j) {
                unsigned p = *(const unsigned*)&hwb[srow[j] * DO + 2 * tid];
                float2 v = bf2x2(p);
                float w = swgt[j];
                ax += w * v.x;
                ay += w * v.y;
            }
        }
        __syncthreads();
    }
    if (tid < ACT) {
        out[n * DO + 2 * tid]     = ax;
        out[n * DO + 2 * tid + 1] = ay;
    }
}

// ---------------------------------------------------------------- batchnorm
__global__ void bn_stats(const float* __restrict__ h, float* __restrict__ stats)
{
    __shared__ float s1[256], s2[256];
    int c = threadIdx.x & 127;
    int half = threadIdx.x >> 7;
    float sum = 0.f, sq = 0.f;
    for (int n = blockIdx.x * 2 + half; n < NN; n += 512) {
        float v = h[n * 128 + c];
        sum += v; sq += v * v;
    }
    s1[threadIdx.x] = sum; s2[threadIdx.x] = sq;
    __syncthreads();
    if (half == 0) {
        s1[c] += s1[c + 128]; s2[c] += s2[c + 128];
        atomicAdd(&stats[c],        s1[c]);
        atomicAdd(&stats[c + 128],  s2[c]);
    }
}

__global__ void bn_apply(float* __restrict__ h, const float* __restrict__ stats,
                         const float* __restrict__ g, const float* __restrict__ b)
{
    int idx = blockIdx.x * 256 + threadIdx.x;
    if (idx >= NN * 128) return;
    int c = idx & 127;
    float mu  = stats[c] * (1.0f / NN);
    float var = stats[c + 128] * (1.0f / NN) - mu * mu;
    h[idx] = (h[idx] - mu) * rsqrtf(var + LN_EPS) * g[c] + b[c];
}

// ---------------------------------------------------------------- launcher
extern "C" void kernel_launch(void* const* d_in, const int* in_sizes, int n_in,
                              void* d_out, int out_size, void* d_ws, size_t ws_size,
                              hipStream_t stream)
{
    auto F = [&](int i) { return (const float*)d_in[i]; };
    const float* x  = F(0);
    const int*   ei = (const int*)d_in[1];
    const float* bn_g = F(23);
    const float* bn_b = F(24);
    // per-conv params: base = 2 + 7*i : ln_g, ln_b, sw, sb, bw, bb, bias

    // ---- workspace layout
    short* wtf0 = (short*)d_ws;                 // 81920 shorts
    short* wtf1 = wtf0 + 81920;                 // 81920
    short* wtf2 = wtf1 + 81920;                 // 92160
    short* hwb  = wtf2 + 92160;                 // NN*128 bf16 (NN*40 for conv2)
    float* dis  = (float*)(hwb + 6400000);      // NN
    float* h1   = dis + 50000;                  // NN*128
    float* h2   = h1  + 6400000;
    float* stats = h2 + 6400000;                // 256
    int*   degi = (int*)(stats + 256);          // NN
    int*   off  = degi + 50000;                 // NN+1
    int*   cur  = off + 50001;                  // NN
    int*   rows = cur + 50000;                  // NE
    int*   histo = rows + NE;                   // 8*NB1 = 1568
    int*   partials = histo + NBKT * NB1;       // NSB+1 = 197
    uint2* staging = (uint2*)h1;                // 12.8 MB, dead until conv0 output
    float* outf = (float*)d_out;

    // ---- CSR build: hist(+degree) -> scans -> partition -> bucket-local scatter
    (void)hipMemsetAsync(degi, 0, 50000 * sizeof(int), stream);
    (void)hipMemsetAsync(cur,  0, 50000 * sizeof(int), stream);
    csr_hist<<<NB1, 256, 0, stream>>>(ei + NE, degi, histo);
    dis_kernel<<<(NN + 255) / 256, 256, 0, stream>>>(degi, dis);
    scan_p1<<<NSB, 256, 0, stream>>>(degi, off, partials);
    scan_p2<<<1, 256, 0, stream>>>(partials);
    scan_p3<<<NSB, 256, 0, stream>>>(off, partials);
    csr_scan2<<<1, 256, 0, stream>>>(histo);
    csr_part<<<NB1, 256, 0, stream>>>(ei, histo, staging);
    csr_scatter<128><<<128 * NBKT, 256, 0, stream>>>(staging, off, cur, rows);

    // ---- pack B fragments (bf16)
    pack_frag<<<(81920 + 255) / 256, 256, 0, stream>>>(F(4),  F(6),  wtf0, 128, 8, 128, 81920);
    pack_frag<<<(81920 + 255) / 256, 256, 0, stream>>>(F(11), F(13), wtf1, 128, 8, 128, 81920);
    pack_frag<<<(92160 + 255) / 256, 256, 0, stream>>>(F(18), F(20), wtf2, 384, 3, 40,  92160);

    const int gridN64 = (NN + 63) / 64;         // 782
    const int gridN32 = (NN + 31) / 32;         // 1563
    const int gridNF  = (NN * 128 + 255) / 256;

    // ---- conv0: x -> h1
    fkan_reg<128, 128, 8, 20, 64><<<gridN64, 256, 0, stream>>>(x, nullptr, nullptr,
        F(2), F(3), wtf0, F(5), F(7), hwb);
    agg_gather_bf16<128><<<NN, 64, 0, stream>>>(off, rows, dis, hwb, F(8), h1);
    (void)hipMemsetAsync(stats, 0, 256 * sizeof(float), stream);
    bn_stats<<<256, 256, 0, stream>>>(h1, stats);
    bn_apply<<<gridNF, 256, 0, stream>>>(h1, stats, bn_g, bn_b);

    // ---- conv1: h1 -> h2
    fkan_reg<128, 128, 8, 20, 64><<<gridN64, 256, 0, stream>>>(h1, nullptr, nullptr,
        F(9), F(10), wtf1, F(12), F(14), hwb);
    agg_gather_bf16<128><<<NN, 64, 0, stream>>>(off, rows, dis, hwb, F(15), h2);
    (void)hipMemsetAsync(stats, 0, 256 * sizeof(float), stream);
    bn_stats<<<256, 256, 0, stream>>>(h2, stats);
    bn_apply<<<gridNF, 256, 0, stream>>>(h2, stats, bn_g, bn_b);

    // ---- conv2: [x|h1|h2] -> d_out
    fkan_reg<384, 40, 3, 60, 32><<<gridN32, 128, 0, stream>>>(x, h1, h2,
        F(16), F(17), wtf2, F(19), F(21), hwb);
    agg_gather_bf16<40><<<NN, 64, 0, stream>>>(off, rows, dis, hwb, F(22), outf);
}